// Round 1
// baseline (25128.345 us; speedup 1.0000x reference)
//
#include <hip/hip_runtime.h>
#include <math.h>

#define T_LEN 512
#define B_SZ  32
#define I_DIM 512
#define H_DIM 1024

// ---------------------------------------------------------------------------
// bias_combine: bias4[4096] = per-gate folded biases
// ---------------------------------------------------------------------------
__global__ void bias_combine(const float* __restrict__ b_ii, const float* __restrict__ b_hi,
                             const float* __restrict__ b_ci, const float* __restrict__ b_if,
                             const float* __restrict__ b_hf, const float* __restrict__ b_cf,
                             const float* __restrict__ b_ic, const float* __restrict__ b_hc,
                             const float* __restrict__ b_io, const float* __restrict__ b_ho,
                             const float* __restrict__ b_cyo, float* __restrict__ bias4) {
    int r = blockIdx.x * 256 + threadIdx.x;
    if (r < H_DIM) {
        bias4[r]            = b_ii[r] + b_hi[r] + b_ci[r];
        bias4[1024 + r]     = b_if[r] + b_hf[r] + b_cf[r];
        bias4[2048 + r]     = b_ic[r] + b_hc[r];
        bias4[3072 + r]     = b_io[r] + b_ho[r] + b_cyo[r];
    }
}

// ---------------------------------------------------------------------------
// pregemm: G[m][n] = sum_k X[m][k] * Wg[nloc][k] + bias4[n]
//   M = chunk rows (Tc*32, multiple of 128), K = 512, N = 4096 (4 gates x 1024)
//   128x128 tile, BK=16, 256 threads, 8x8 per thread.
// ---------------------------------------------------------------------------
#define BM 128
#define BN 128
#define BK 16
__global__ __launch_bounds__(256) void pregemm(const float* __restrict__ A,
                                               const float* __restrict__ w0,
                                               const float* __restrict__ w1,
                                               const float* __restrict__ w2,
                                               const float* __restrict__ w3,
                                               const float* __restrict__ bias4,
                                               float* __restrict__ C) {
    __shared__ float As[BK][BM + 4];
    __shared__ float Bs[BK][BN + 4];
    int tid = threadIdx.x;
    int n0 = blockIdx.y * BN;
    const float* W = (n0 < 1024) ? w0 : (n0 < 2048) ? w1 : (n0 < 3072) ? w2 : w3;
    int nloc = n0 & 1023;

    int lr = tid >> 2;            // 0..63
    int lk = (tid & 3) << 2;      // 0,4,8,12
    const float* Arow = A + (size_t)(blockIdx.x * BM + lr) * I_DIM + lk;
    const float* Brow = W + (size_t)(nloc + lr) * I_DIM + lk;

    float acc[8][8];
#pragma unroll
    for (int i = 0; i < 8; ++i)
#pragma unroll
        for (int j = 0; j < 8; ++j) acc[i][j] = 0.f;

    int mth = (tid >> 4) << 3;    // 0..120
    int nth = (tid & 15) << 3;    // 0..120

    for (int kt = 0; kt < I_DIM; kt += BK) {
        float4 a0 = *(const float4*)(Arow + kt);
        float4 a1 = *(const float4*)(Arow + 64 * I_DIM + kt);
        float4 b0 = *(const float4*)(Brow + kt);
        float4 b1 = *(const float4*)(Brow + 64 * I_DIM + kt);
        __syncthreads();
        As[lk + 0][lr] = a0.x; As[lk + 1][lr] = a0.y; As[lk + 2][lr] = a0.z; As[lk + 3][lr] = a0.w;
        As[lk + 0][lr + 64] = a1.x; As[lk + 1][lr + 64] = a1.y; As[lk + 2][lr + 64] = a1.z; As[lk + 3][lr + 64] = a1.w;
        Bs[lk + 0][lr] = b0.x; Bs[lk + 1][lr] = b0.y; Bs[lk + 2][lr] = b0.z; Bs[lk + 3][lr] = b0.w;
        Bs[lk + 0][lr + 64] = b1.x; Bs[lk + 1][lr + 64] = b1.y; Bs[lk + 2][lr + 64] = b1.z; Bs[lk + 3][lr + 64] = b1.w;
        __syncthreads();
#pragma unroll
        for (int j = 0; j < BK; ++j) {
            float am[8], bn[8];
            *(float4*)&am[0] = *(const float4*)&As[j][mth];
            *(float4*)&am[4] = *(const float4*)&As[j][mth + 4];
            *(float4*)&bn[0] = *(const float4*)&Bs[j][nth];
            *(float4*)&bn[4] = *(const float4*)&Bs[j][nth + 4];
#pragma unroll
            for (int ii = 0; ii < 8; ++ii)
#pragma unroll
                for (int jj = 0; jj < 8; ++jj) acc[ii][jj] += am[ii] * bn[jj];
        }
    }

    float bb[8];
    *(float4*)&bb[0] = *(const float4*)&bias4[n0 + nth];
    *(float4*)&bb[4] = *(const float4*)&bias4[n0 + nth + 4];
    size_t mbase = (size_t)(blockIdx.x * BM + mth);
#pragma unroll
    for (int ii = 0; ii < 8; ++ii) {
        float* crow = C + (mbase + ii) * 4096 + n0 + nth;
        float4 v0, v1;
        v0.x = acc[ii][0] + bb[0]; v0.y = acc[ii][1] + bb[1];
        v0.z = acc[ii][2] + bb[2]; v0.w = acc[ii][3] + bb[3];
        v1.x = acc[ii][4] + bb[4]; v1.y = acc[ii][5] + bb[5];
        v1.z = acc[ii][6] + bb[6]; v1.w = acc[ii][7] + bb[7];
        *(float4*)crow = v0;
        *(float4*)(crow + 4) = v1;
    }
}

// ---------------------------------------------------------------------------
// phaseA (one per timestep): given h(t-1), c(t-1), gate precomps Gt:
//   i = sig(xi + h@w_hi^T + c@w_ci^T); f = sig(xf + h@w_hf^T + c@w_cf^T)
//   g = tanh(xg + h@w_hc^T); cy = f*c + i*g  -> c_out
//   po = xo + h@w_ho^T                       -> po_buf
// grid 256 blocks x 512 thr; wave w: row = blk*4 + (w&3), kgroup = w>>2.
// lane: half = lane>>5, b = lane&31. k chunked by 128 into LDS.
// ---------------------------------------------------------------------------
__global__ __launch_bounds__(512) void phaseA(const float* __restrict__ h_in,
                                              const float* __restrict__ c_in,
                                              const float* __restrict__ Gt,
                                              const float* __restrict__ w_hi,
                                              const float* __restrict__ w_ci,
                                              const float* __restrict__ w_hf,
                                              const float* __restrict__ w_cf,
                                              const float* __restrict__ w_hc,
                                              const float* __restrict__ w_ho,
                                              float* __restrict__ c_out,
                                              float* __restrict__ po_buf) {
    __shared__ float hs[32][132];
    __shared__ float cs[32][132];
    __shared__ float red6[4][6][32];

    int tid = threadIdx.x;
    int wv = tid >> 6;            // 0..7
    int lane = tid & 63;
    int rw = wv & 3;
    int kg = wv >> 2;             // 0/1 -> k half
    int half = lane >> 5;         // 0/1 -> k quarter within half
    int b = lane & 31;
    int r = blockIdx.x * 4 + rw;

    const float* whi = w_hi + (size_t)r * H_DIM;
    const float* wci = w_ci + (size_t)r * H_DIM;
    const float* whf = w_hf + (size_t)r * H_DIM;
    const float* wcf = w_cf + (size_t)r * H_DIM;
    const float* whc = w_hc + (size_t)r * H_DIM;
    const float* who = w_ho + (size_t)r * H_DIM;

    float acc0 = 0.f, acc1 = 0.f, acc2 = 0.f, acc3 = 0.f, acc4 = 0.f, acc5 = 0.f;

    int bb = tid >> 4;            // 0..31 (staging row)
    int slot = tid & 15;          // 0..15
    int klbase = kg * 64 + half * 32;

    for (int c = 0; c < 8; ++c) {
        int k0 = c * 128;
        __syncthreads();
        {
            const float* hrow = h_in + (size_t)bb * H_DIM + k0;
            const float* crow = c_in + (size_t)bb * H_DIM + k0;
            int kk = slot * 4;
            *(float4*)&hs[bb][kk]      = *(const float4*)(hrow + kk);
            *(float4*)&hs[bb][kk + 64] = *(const float4*)(hrow + kk + 64);
            *(float4*)&cs[bb][kk]      = *(const float4*)(crow + kk);
            *(float4*)&cs[bb][kk + 64] = *(const float4*)(crow + kk + 64);
        }
        __syncthreads();
#pragma unroll 4
        for (int j = 0; j < 8; ++j) {
            int kl = klbase + j * 4;
            float4 h4 = *(const float4*)&hs[b][kl];
            float4 c4 = *(const float4*)&cs[b][kl];
            int kgk = k0 + kl;
            float4 w;
            w = *(const float4*)(whi + kgk);
            acc0 += w.x * h4.x + w.y * h4.y + w.z * h4.z + w.w * h4.w;
            w = *(const float4*)(wci + kgk);
            acc1 += w.x * c4.x + w.y * c4.y + w.z * c4.z + w.w * c4.w;
            w = *(const float4*)(whf + kgk);
            acc2 += w.x * h4.x + w.y * h4.y + w.z * h4.z + w.w * h4.w;
            w = *(const float4*)(wcf + kgk);
            acc3 += w.x * c4.x + w.y * c4.y + w.z * c4.z + w.w * c4.w;
            w = *(const float4*)(whc + kgk);
            acc4 += w.x * h4.x + w.y * h4.y + w.z * h4.z + w.w * h4.w;
            w = *(const float4*)(who + kgk);
            acc5 += w.x * h4.x + w.y * h4.y + w.z * h4.z + w.w * h4.w;
        }
    }

    // combine the two 32-lane halves within the wave
    acc0 += __shfl_xor(acc0, 32);
    acc1 += __shfl_xor(acc1, 32);
    acc2 += __shfl_xor(acc2, 32);
    acc3 += __shfl_xor(acc3, 32);
    acc4 += __shfl_xor(acc4, 32);
    acc5 += __shfl_xor(acc5, 32);

    if (kg == 1 && half == 0) {
        red6[rw][0][b] = acc0; red6[rw][1][b] = acc1; red6[rw][2][b] = acc2;
        red6[rw][3][b] = acc3; red6[rw][4][b] = acc4; red6[rw][5][b] = acc5;
    }
    __syncthreads();
    if (kg == 0 && half == 0) {
        acc0 += red6[rw][0][b]; acc1 += red6[rw][1][b]; acc2 += red6[rw][2][b];
        acc3 += red6[rw][3][b]; acc4 += red6[rw][4][b]; acc5 += red6[rw][5][b];
        const float* Gb = Gt + (size_t)b * 4096;
        float xi = Gb[r];
        float xf = Gb[1024 + r];
        float xg = Gb[2048 + r];
        float xo = Gb[3072 + r];
        float iv = 1.f / (1.f + expf(-(xi + acc0 + acc1)));
        float fv = 1.f / (1.f + expf(-(xf + acc2 + acc3)));
        float gv = tanhf(xg + acc4);
        int idx = b * H_DIM + r;
        float cy = fv * c_in[idx] + iv * gv;
        c_out[idx] = cy;
        po_buf[idx] = xo + acc5;
    }
}

// ---------------------------------------------------------------------------
// phaseB (one per timestep): o = sig(po + cy@w_cyo^T); hy = o*tanh(cy) -> out[t]
// grid 256 blocks x 256 thr; 4 rows/block; 2-way k-split across wave pairs.
// ---------------------------------------------------------------------------
__global__ __launch_bounds__(256) void phaseB(const float* __restrict__ cy_in,
                                              const float* __restrict__ po_buf,
                                              const float* __restrict__ w_cyo,
                                              float* __restrict__ outT) {
    __shared__ float cs0[32][132];
    __shared__ float cs1[32][132];
    __shared__ float red[4][32];

    int tid = threadIdx.x;
    int wv = tid >> 6;            // 0..3
    int lane = tid & 63;
    int kg = wv >> 1;             // 0/1
    int ri = ((wv & 1) << 1) | (lane >> 5);
    int b = lane & 31;
    int r = blockIdx.x * 4 + ri;
    const float* wrow = w_cyo + (size_t)r * H_DIM;

    float acc = 0.f;
    int bb = tid >> 3;            // 0..31
    int slot = tid & 7;           // 0..7

    for (int cp = 0; cp < 4; ++cp) {
        __syncthreads();
        {
            const float* crow = cy_in + (size_t)bb * H_DIM;
#pragma unroll
            for (int i = 0; i < 4; ++i) {
                int kk = (slot + i * 8) * 4;
                *(float4*)&cs0[bb][kk] = *(const float4*)(crow + cp * 128 + kk);
                *(float4*)&cs1[bb][kk] = *(const float4*)(crow + 512 + cp * 128 + kk);
            }
        }
        __syncthreads();
        const float(*csl)[132] = (kg == 0) ? cs0 : cs1;
        int k0 = kg * 512 + cp * 128;
#pragma unroll 8
        for (int j = 0; j < 32; ++j) {
            float4 c4 = *(const float4*)&csl[b][j * 4];
            float4 w4 = *(const float4*)(wrow + k0 + j * 4);
            acc += w4.x * c4.x + w4.y * c4.y + w4.z * c4.z + w4.w * c4.w;
        }
    }

    if (kg == 1) red[ri][b] = acc;
    __syncthreads();
    if (kg == 0) {
        acc += red[ri][b];
        int idx = b * H_DIM + r;
        float cyv = cy_in[idx];
        float o = 1.f / (1.f + expf(-(po_buf[idx] + acc)));
        outT[idx] = o * tanhf(cyv);
    }
}

// ---------------------------------------------------------------------------
extern "C" void kernel_launch(void* const* d_in, const int* in_sizes, int n_in,
                              void* d_out, int out_size, void* d_ws, size_t ws_size,
                              hipStream_t stream) {
    const float* X     = (const float*)d_in[0];
    const float* h0    = (const float*)d_in[1];
    const float* c0    = (const float*)d_in[2];
    const float* w_ii  = (const float*)d_in[3];
    const float* w_hi  = (const float*)d_in[4];
    const float* w_ci  = (const float*)d_in[5];
    const float* w_if  = (const float*)d_in[6];
    const float* w_hf  = (const float*)d_in[7];
    const float* w_cf  = (const float*)d_in[8];
    const float* w_ic  = (const float*)d_in[9];
    const float* w_hc  = (const float*)d_in[10];
    const float* w_io  = (const float*)d_in[11];
    const float* w_ho  = (const float*)d_in[12];
    const float* w_cyo = (const float*)d_in[13];
    const float* b_ii  = (const float*)d_in[14];
    const float* b_hi  = (const float*)d_in[15];
    const float* b_ci  = (const float*)d_in[16];
    const float* b_if  = (const float*)d_in[17];
    const float* b_hf  = (const float*)d_in[18];
    const float* b_cf  = (const float*)d_in[19];
    const float* b_ic  = (const float*)d_in[20];
    const float* b_hc  = (const float*)d_in[21];
    const float* b_io  = (const float*)d_in[22];
    const float* b_ho  = (const float*)d_in[23];
    const float* b_cyo = (const float*)d_in[24];
    float* out = (float*)d_out;

    // workspace carve: G chunk + bias4 + c ping-pong + po buffer
    const size_t state_floats = 4096 + 2 * (size_t)B_SZ * H_DIM + (size_t)B_SZ * H_DIM;
    int Tc = 512;
    while (Tc > 4 && (size_t)Tc * 32 * 4096 * 4 + state_floats * 4 + 256 > ws_size) Tc >>= 1;

    float* G     = (float*)d_ws;
    float* bias4 = G + (size_t)Tc * 32 * 4096;
    float* cpp   = bias4 + 4096;
    float* po    = cpp + 2 * (size_t)B_SZ * H_DIM;

    bias_combine<<<4, 256, 0, stream>>>(b_ii, b_hi, b_ci, b_if, b_hf, b_cf,
                                        b_ic, b_hc, b_io, b_ho, b_cyo, bias4);

    for (int t0 = 0; t0 < T_LEN; t0 += Tc) {
        pregemm<<<dim3(Tc * 32 / BM, 4096 / BN), 256, 0, stream>>>(
            X + (size_t)t0 * B_SZ * I_DIM, w_ii, w_if, w_ic, w_io, bias4, G);
        for (int t = t0; t < t0 + Tc; ++t) {
            const float* h_in = (t == 0) ? h0 : out + (size_t)(t - 1) * B_SZ * H_DIM;
            const float* c_in = (t == 0) ? c0 : cpp + (size_t)(t & 1) * B_SZ * H_DIM;
            float* c_out = cpp + (size_t)((t + 1) & 1) * B_SZ * H_DIM;
            const float* Gt = G + (size_t)(t - t0) * B_SZ * 4096;
            phaseA<<<256, 512, 0, stream>>>(h_in, c_in, Gt, w_hi, w_ci, w_hf,
                                            w_cf, w_hc, w_ho, c_out, po);
            phaseB<<<256, 256, 0, stream>>>(c_out, po, w_cyo,
                                            out + (size_t)t * B_SZ * H_DIM);
        }
    }
}